// Round 10
// baseline (336.213 us; speedup 1.0000x reference)
//
#include <hip/hip_runtime.h>
#include <hip/hip_bf16.h>
#include <math.h>

// ---------------------------------------------------------------------------
// CrossModalAttention on MI355X (gfx950)
//   B=4, Cu=320, Cj=1024, H=W=64 (N=4096), ATTN_DIM=256, scale = 1/16
// Round 9: attn reads K directly from L2 in MFMA-fragment order (K' emitted
// by the K-projection GEMM, new EPI3) — no LDS K staging, no kbuf, no vmcnt
// drains. attn LDS 75KB -> 21.5KB so 2+ blocks/CU reside; latency hidden by
// TLP. Wave-specialized roles kept from R8 (2 QK + 4 PV per 384-thr block).
// Epilogue merges jw halves in-place in bf16 (aliases pbuf after the loop).
// ---------------------------------------------------------------------------

typedef unsigned short u16;
typedef __attribute__((ext_vector_type(8))) short bf16x8;
typedef __attribute__((ext_vector_type(4))) float f32x4;
typedef __attribute__((ext_vector_type(16))) float f32x16;
typedef __attribute__((ext_vector_type(4))) unsigned short u16x4;

#define NB 4
#define CU 320
#define CJ 1024
#define NN 4096
#define AD 256

// ws layout (bytes)
#define XU_OFF 0u
#define XJ_OFF 10485760u
#define QB_OFF 44040192u
#define KB_OFF 52428800u
#define VB_OFF 60817408u
#define WQ_OFF 71303168u
#define WK_OFF 71467008u
#define WV_OFF 71991296u
#define WO_OFF 72646656u
#define AO_OFF XU_OFF

__device__ __forceinline__ u16 f2b(float f) {
    union { float f; unsigned u; } v; v.f = f;
    unsigned u = v.u;
    unsigned r = (u + 0x7fffu + ((u >> 16) & 1u)) >> 16;
    return (u16)r;
}

__device__ __forceinline__ float b2f(u16 x) {
    union { unsigned u; float f; } v; v.u = ((unsigned)x) << 16;
    return v.f;
}

__device__ __forceinline__ unsigned cvt_pk_bf16(float lo, float hi) {
    unsigned r;
    asm("v_cvt_pk_bf16_f32 %0, %1, %2" : "=v"(r) : "v"(lo), "v"(hi));
    return r;
}

__device__ __forceinline__ float exp2_fast(float x) {
    float r;
    asm("v_exp_f32 %0, %1" : "=v"(r) : "v"(x));
    return r;
}

__device__ __forceinline__ void async_cp16(const u16* g, char* l) {
    __builtin_amdgcn_global_load_lds(
        (const __attribute__((address_space(1))) unsigned int*)g,
        (__attribute__((address_space(3))) unsigned int*)l, 16, 0, 0);
}

// ---------------- weight cast ----------------
__global__ void wcast_kernel(const float* __restrict__ Wq, const float* __restrict__ Wk,
                             const float* __restrict__ Wv, const float* __restrict__ Wo,
                             u16* __restrict__ wq, u16* __restrict__ wk,
                             u16* __restrict__ wv, u16* __restrict__ wo) {
    int id = blockIdx.x * 256 + threadIdx.x;
    if (id < 81920) { wq[id] = f2b(Wq[id]); return; }
    id -= 81920;
    if (id < 262144) { wk[id] = f2b(Wk[id]); return; }
    id -= 262144;
    if (id < 327680) { wv[id] = f2b(Wv[id]); return; }
    id -= 327680;
    if (id < 102400) { wo[id] = f2b(Wo[id]); }
}

// ---------------- transpose [C][N] f32 -> [N][C] bf16 ----------------
__global__ __launch_bounds__(256) void transpose_cast_kernel(
        const float* __restrict__ in, u16* __restrict__ out, int C, int Nn) {
    __shared__ float tile[64][65];
    int b = blockIdx.z;
    int n0 = blockIdx.x * 64, c0 = blockIdx.y * 64;
    const float* src = in + (size_t)b * C * Nn;
    u16* dst = out + (size_t)b * Nn * C;
    int t = threadIdx.x;
    int nl = t & 63, cl = t >> 6;
    #pragma unroll
    for (int k = 0; k < 16; ++k) {
        int c = cl + k * 4;
        tile[c][nl] = src[(size_t)(c0 + c) * Nn + n0 + nl];
    }
    __syncthreads();
    int cl2 = t & 63, nl2 = t >> 6;
    #pragma unroll
    for (int k = 0; k < 16; ++k) {
        int n = nl2 + k * 4;
        dst[(size_t)(n0 + n) * C + c0 + cl2] = f2b(tile[cl2][n]);
    }
}

// ---------------- unified GEMM: out = A(16384xKD) @ W(NOUTxKD)^T ----------------
// EPI 0: bf16 out [M][NOUT], val=(acc+bias)*alpha            (Q)
// EPI 1: bf16 out in MFMA-fragment order V'[ct][j16][lane][8] (V)
// EPI 2: f32  out [b][o][n] transposed + bias + unet res     (final)
// EPI 3: bf16 out in MFMA A-fragment order K'[jt][kk][lane][8](K)
template <int EPI, int KD, int NOUT>
__global__ __launch_bounds__(256, 2) void gemm_kernel(
        const u16* __restrict__ A, const u16* __restrict__ W,
        const float* __restrict__ bias, void* __restrict__ outp,
        const float* __restrict__ unet, float alpha) {
    __shared__ __align__(16) char smem[49152];
    const int t = threadIdx.x;
    const int lane = t & 63, wave = t >> 6;
    const int r = lane & 15, h = lane >> 4;
    const int wr = wave >> 1, wc = wave & 1;
    const int m0 = blockIdx.x * 128;
    const int bn0 = blockIdx.y * 64;

    int goffA[4], goffB[2];
    #pragma unroll
    for (int n = 0; n < 4; ++n) {
        int c = n * 256 + t;
        int row = c >> 3, s = c & 7;
        goffA[n] = (m0 + row) * KD + ((s ^ (row & 7)) << 3);
    }
    #pragma unroll
    for (int n = 0; n < 2; ++n) {
        int c = n * 256 + t;
        int row = c >> 3, s = c & 7;
        goffB[n] = (bn0 + row) * KD + ((s ^ (row & 7)) << 3);
    }
    const unsigned wb = (unsigned)(t & ~63) * 16u;

    #define GSTAGE(BUF, KT) do {                                                  \
        _Pragma("unroll")                                                         \
        for (int n_ = 0; n_ < 4; ++n_)                                            \
            async_cp16(A + goffA[n_] + (KT) * 64,                                 \
                       smem + (BUF) * 24576 + n_ * 4096 + wb);                    \
        _Pragma("unroll")                                                         \
        for (int n_ = 0; n_ < 2; ++n_)                                            \
            async_cp16(W + goffB[n_] + (KT) * 64,                                 \
                       smem + (BUF) * 24576 + 16384 + n_ * 4096 + wb);            \
    } while (0)

    f32x4 acc[4][2];
    #pragma unroll
    for (int fr = 0; fr < 4; ++fr)
        #pragma unroll
        for (int fc = 0; fc < 2; ++fc) acc[fr][fc] = (f32x4)0.0f;

    GSTAGE(0, 0);
    int buf = 0;
    const int KS = KD / 64;
    for (int kt = 0; kt < KS; ++kt) {
        if (kt < KS - 1) {
            GSTAGE(buf ^ 1, kt + 1);
            asm volatile("s_waitcnt vmcnt(6)" ::: "memory");
        } else {
            asm volatile("s_waitcnt vmcnt(0)" ::: "memory");
        }
        __builtin_amdgcn_s_barrier();
        asm volatile("" ::: "memory");
        const char* Ab = smem + buf * 24576;
        const char* Bb = smem + buf * 24576 + 16384;
        #pragma unroll
        for (int kk = 0; kk < 2; ++kk) {
            bf16x8 af[4], bf[2];
            #pragma unroll
            for (int fr = 0; fr < 4; ++fr) {
                int row = wr * 64 + fr * 16 + r;
                af[fr] = *(const bf16x8*)(Ab + row * 128 + (((kk * 4 + h) ^ (row & 7)) << 4));
            }
            #pragma unroll
            for (int fc = 0; fc < 2; ++fc) {
                int rowb = wc * 32 + fc * 16 + r;
                bf[fc] = *(const bf16x8*)(Bb + rowb * 128 + (((kk * 4 + h) ^ (rowb & 7)) << 4));
            }
            #pragma unroll
            for (int fr = 0; fr < 4; ++fr)
                #pragma unroll
                for (int fc = 0; fc < 2; ++fc)
                    acc[fr][fc] = __builtin_amdgcn_mfma_f32_16x16x32_bf16(
                        af[fr], bf[fc], acc[fr][fc], 0, 0, 0);
        }
        asm volatile("" ::: "memory");
        __builtin_amdgcn_s_barrier();
        asm volatile("" ::: "memory");
        buf ^= 1;
    }
    #undef GSTAGE

    const int mw = m0 + wr * 64;
    const int ob0 = bn0 + wc * 32;

    if (EPI == 0) {
        u16* out = (u16*)outp;
        #pragma unroll
        for (int fc = 0; fc < 2; ++fc) {
            int o = ob0 + fc * 16 + r;
            float bs = bias[o];
            #pragma unroll
            for (int fr = 0; fr < 4; ++fr)
                #pragma unroll
                for (int rr = 0; rr < 4; ++rr) {
                    int mrow = mw + fr * 16 + h * 4 + rr;
                    out[(size_t)mrow * NOUT + o] = f2b((acc[fr][fc][rr] + bs) * alpha);
                }
        }
    } else if (EPI == 1) {
        // transpose via LDS then store in MFMA B-fragment order V'[b][ct][j16][lane][8]
        u16* tile = (u16*)(smem + wave * 4608);
        #pragma unroll
        for (int fc = 0; fc < 2; ++fc) {
            int o = ob0 + fc * 16 + r;
            float bs = bias[o];
            #pragma unroll
            for (int fr = 0; fr < 4; ++fr) {
                u16x4 v4;
                #pragma unroll
                for (int rr = 0; rr < 4; ++rr) v4[rr] = f2b(acc[fr][fc][rr] + bs);
                *(u16x4*)(tile + (fc * 16 + r) * 72 + fr * 16 + h * 4) = v4;
            }
        }
        __builtin_amdgcn_s_waitcnt(0);
        u16* Vout = (u16*)outp;
        int bb = mw >> 12, nb = mw & 4095;
        #pragma unroll
        for (int g = 0; g < 4; ++g) {
            int chunk = g * 64 + lane;
            int row = chunk >> 3, ns = chunk & 7;
            int ch = ob0 + row;
            int j = nb + ns * 8;
            bf16x8 val = *(const bf16x8*)(tile + row * 72 + ns * 8);
            size_t off = (size_t)bb * CU * NN + (size_t)(ch >> 5) * (NN * 32)
                       + (size_t)(j >> 4) * 512
                       + (size_t)((ch & 31) + ((j >> 3) & 1) * 32) * 8 + (j & 7);
            *(bf16x8*)(Vout + off) = val;
        }
    } else if (EPI == 2) {
        float* tile = (float*)(smem + wave * 8704);   // [32][68] f32
        #pragma unroll
        for (int fc = 0; fc < 2; ++fc)
            #pragma unroll
            for (int fr = 0; fr < 4; ++fr)
                *(f32x4*)(tile + (fc * 16 + r) * 68 + fr * 16 + h * 4) = acc[fr][fc];
        __builtin_amdgcn_s_waitcnt(0);
        float* out = (float*)outp;
        int bb = mw >> 12, nb = mw & 4095;
        #pragma unroll
        for (int g = 0; g < 8; ++g) {
            int chunk = g * 64 + lane;
            int row = chunk >> 4, ns = chunk & 15;
            int o = ob0 + row;
            size_t base = (size_t)bb * CU * NN + (size_t)o * NN + nb + ns * 4;
            f32x4 v = *(const f32x4*)(tile + row * 68 + ns * 4);
            f32x4 u = *(const f32x4*)(unet + base);
            float bs = bias[o];
            f32x4 res;
            #pragma unroll
            for (int rr = 0; rr < 4; ++rr) res[rr] = v[rr] + bs + u[rr];
            *(f32x4*)(out + base) = res;
        }
    } else {
        // EPI 3: K in MFMA A-fragment order K'[b][jt 128][kk 16][lane 64][e 8]
        u16* out = (u16*)outp;
        #pragma unroll
        for (int fc = 0; fc < 2; ++fc) {
            int o = ob0 + fc * 16 + r;
            float bs = bias[o];
            int kk = o >> 4, hi5 = (o >> 3) & 1, e = o & 7;
            #pragma unroll
            for (int fr = 0; fr < 4; ++fr)
                #pragma unroll
                for (int rr = 0; rr < 4; ++rr) {
                    int mrow = mw + fr * 16 + h * 4 + rr;
                    int bb = mrow >> 12, jin = mrow & 4095;
                    size_t off = (size_t)bb * (NN * AD) + (size_t)(jin >> 5) * 8192
                               + kk * 512 + (hi5 * 32 + (jin & 31)) * 8 + e;
                    out[off] = f2b(acc[fr][fc][rr] + bs);
                }
        }
    }
}

// ---------------- flash attention (round-9: no K staging) ----------------
// Q: [B][N][256] bf16 (pre-scaled log2e/16),
// K': [B][jt 128][kk 16][lane 64][8] bf16 (A-fragment order, from EPI3),
// V': [B][ct 10][j16 256][lane 64][8] bf16 (B-fragment order, from EPI1).
// 512 blocks x 384 thr (6 waves): waves 0-1 = QK(jw), waves 2-5 = PV(pj,pc).
// LDS 21504B: pbuf 2 parity x 4608 @0 (P frags @0..4096, al @4096, flag @4352);
// mlb @20992. Epilogue: in-place bf16 [32][328] @0 (aliases pbuf after loop).
__global__ __launch_bounds__(384, 3) void attn_kernel(
        const u16* __restrict__ Q, const u16* __restrict__ Kf,
        const u16* __restrict__ V, u16* __restrict__ AO) {
    __shared__ __align__(16) char smem[21504];

    const int t = threadIdx.x;
    const int lane = t & 63;
    const int wave = t >> 6;          // 0..5
    const int r = lane & 31, hi = lane >> 5;

    int linear = blockIdx.x;
    int swz = (linear & 7) * 64 + (linear >> 3);
    int b = swz >> 7;
    int i0 = (swz & 127) * 32;

    const u16* Qb = Q + ((size_t)b * NN + i0) * AD;
    const u16* Kb = Kf + (size_t)b * (NN * AD);
    const u16* Vb = V + (size_t)b * CU * NN;

    if (wave < 2) {
        // ================= QK role =================
        const int jw = wave;
        bf16x8 q[16];
        #pragma unroll
        for (int kk = 0; kk < 16; ++kk)
            q[kk] = *(const bf16x8*)(Qb + (size_t)r * AD + kk * 16 + hi * 8);
        float m = -INFINITY, lsum = 0.0f;
        const u16* kp0 = Kb + (size_t)jw * 8192 + lane * 8;

        for (int i = 0; i < 64; ++i) {
            __builtin_amdgcn_s_barrier();
            asm volatile("" ::: "memory");

            const u16* kp = kp0 + (size_t)i * 16384;
            // QK: two 8-deep batches (bounds VGPR pressure)
            bf16x8 kf[8];
            #pragma unroll
            for (int kk = 0; kk < 8; ++kk)
                kf[kk] = *(const bf16x8*)(kp + kk * 512);
            f32x16 sa = (f32x16)0.0f, sb = (f32x16)0.0f;
            __builtin_amdgcn_s_setprio(1);
            #pragma unroll
            for (int kk = 0; kk < 8; ++kk)
                sa = __builtin_amdgcn_mfma_f32_32x32x16_bf16(kf[kk], q[kk], sa, 0, 0, 0);
            #pragma unroll
            for (int kk = 0; kk < 8; ++kk)
                kf[kk] = *(const bf16x8*)(kp + (8 + kk) * 512);
            #pragma unroll
            for (int kk = 0; kk < 8; ++kk)
                sb = __builtin_amdgcn_mfma_f32_32x32x16_bf16(kf[kk], q[kk + 8], sb, 0, 0, 0);
            __builtin_amdgcn_s_setprio(0);
            f32x16 s = sa + sb;

            // softmax (exp2 domain, defer-max THR=8)
            float x0 = fmaxf(s[0], s[1]),   x1 = fmaxf(s[2], s[3]);
            float x2 = fmaxf(s[4], s[5]),   x3 = fmaxf(s[6], s[7]);
            float x4 = fmaxf(s[8], s[9]),   x5 = fmaxf(s[10], s[11]);
            float x6 = fmaxf(s[12], s[13]), x7 = fmaxf(s[14], s[15]);
            float pmax = fmaxf(fmaxf(fmaxf(x0, x1), fmaxf(x2, x3)),
                               fmaxf(fmaxf(x4, x5), fmaxf(x6, x7)));
            pmax = fmaxf(pmax, __shfl_xor(pmax, 32));
            char* pb = smem + (i & 1) * 4608;
            int fl = __any(pmax > m + 8.0f) ? 1 : 0;
            if (fl) {
                float mn = fmaxf(m, pmax);
                float al = exp2_fast(m - mn);
                m = mn;
                lsum *= al;
                if (lane < 32) *(float*)(pb + 4096 + jw * 128 + r * 4) = al;
            }
            if (lane == 0) *(int*)(pb + 4352 + jw * 4) = fl;
            float p[16];
            #pragma unroll
            for (int e = 0; e < 16; ++e) p[e] = exp2_fast(s[e] - m);
            float y0 = (p[0] + p[1]) + (p[2] + p[3]);
            float y1 = (p[4] + p[5]) + (p[6] + p[7]);
            float y2 = (p[8] + p[9]) + (p[10] + p[11]);
            float y3 = (p[12] + p[13]) + (p[14] + p[15]);
            float ps = (y0 + y1) + (y2 + y3);
            ps += __shfl_xor(ps, 32);
            lsum += ps;

            // P -> B-operand fragments, write to pbuf
            #pragma unroll
            for (int ks = 0; ks < 2; ++ks) {
                unsigned a0 = cvt_pk_bf16(p[8 * ks + 0], p[8 * ks + 1]);
                unsigned a1 = cvt_pk_bf16(p[8 * ks + 2], p[8 * ks + 3]);
                unsigned b0 = cvt_pk_bf16(p[8 * ks + 4], p[8 * ks + 5]);
                unsigned b1 = cvt_pk_bf16(p[8 * ks + 6], p[8 * ks + 7]);
                asm("v_permlane32_swap_b32 %0, %1" : "+v"(a0), "+v"(b0));
                asm("v_permlane32_swap_b32 %0, %1" : "+v"(a1), "+v"(b1));
                union { unsigned w[4]; bf16x8 v; } u;
                u.w[0] = a0; u.w[1] = a1; u.w[2] = b0; u.w[3] = b1;
                *(bf16x8*)(pb + jw * 2048 + ks * 1024 + lane * 16) = u.v;
            }
            asm volatile("s_waitcnt lgkmcnt(0)" ::: "memory");
            __builtin_amdgcn_sched_barrier(0);
        }
        __builtin_amdgcn_s_barrier();   // P(63) published
        asm volatile("" ::: "memory");
        if (lane < 32) {
            *(float*)(smem + 20992 + jw * 128 + r * 4) = m;
            *(float*)(smem + 20992 + 256 + jw * 128 + r * 4) = lsum;
        }
        __syncthreads();    // syncA
        __syncthreads();    // syncB
        __syncthreads();    // syncC
    } else {
        // ================= PV role =================
        const int pvid = wave - 2;
        const int pj = pvid & 1;        // which jw's P
        const int pc = pvid >> 1;       // 160-ch half
        f32x16 o[5];
        #pragma unroll
        for (int ct = 0; ct < 5; ++ct) o[ct] = (f32x16)0.0f;
        const u16* vb = Vb + (size_t)(pc * 5) * 131072 + lane * 8;

        #define PV_BODY(TI) do {                                                  \
            const char* pb = smem + ((TI) & 1) * 4608;                            \
            int fl = *(volatile const int*)(pb + 4352 + pj * 4);                  \
            bf16x8 vfA[5], vfB[5];                                                \
            _Pragma("unroll")                                                     \
            for (int c = 0; c < 5; ++c)                                           \
                vfA[c] = *(const bf16x8*)(vb + (size_t)c * 131072 +               \
                                          ((TI) * 4 + pj * 2 + 0) * 512);         \
            _Pragma("unroll")                                                     \
            for (int c = 0; c < 5; ++c)                                           \
                vfB[c] = *(const bf16x8*)(vb + (size_t)c * 131072 +               \
                                          ((TI) * 4 + pj * 2 + 1) * 512);         \
            bf16x8 pf0 = *(const bf16x8*)(pb + pj * 2048 + lane * 16);            \
            bf16x8 pf1 = *(const bf16x8*)(pb + pj * 2048 + 1024 + lane * 16);     \
            if (fl) {                                                             \
                float alv = *(volatile const float*)(pb + 4096 + pj * 128 +       \
                                                     (lane & 31) * 4);            \
                _Pragma("unroll")                                                 \
                for (int ct = 0; ct < 5; ++ct) o[ct] *= alv;                      \
            }                                                                     \
            __builtin_amdgcn_s_setprio(1);                                        \
            _Pragma("unroll")                                                     \
            for (int ct = 0; ct < 5; ++ct)                                        \
                o[ct] = __builtin_amdgcn_mfma_f32_32x32x16_bf16(vfA[ct], pf0,     \
                                                                o[ct], 0, 0, 0); \
            _Pragma("unroll")                                                     \
            for (int ct = 0; ct < 5; ++ct)                                        \
                o[ct] = __builtin_amdgcn_mfma_f32_32x32x16_bf16(vfB[ct], pf1,     \
                                                                o[ct], 0, 0, 0); \
            __builtin_amdgcn_s_setprio(0);                                        \
        } while (0)

        for (int i = 0; i < 64; ++i) {
            __builtin_amdgcn_s_barrier();
            asm volatile("" ::: "memory");
            if (i >= 1) PV_BODY(i - 1);
        }
        __builtin_amdgcn_s_barrier();   // P(63) published
        asm volatile("" ::: "memory");
        PV_BODY(63);

        __syncthreads();    // syncA: m/l published, pbuf dead
        float m0 = *(const float*)(smem + 20992 + pj * 128 + r * 4);
        float l0 = *(const float*)(smem + 20992 + 256 + pj * 128 + r * 4);
        float m1 = *(const float*)(smem + 20992 + (pj ^ 1) * 128 + r * 4);
        float l1 = *(const float*)(smem + 20992 + 256 + (pj ^ 1) * 128 + r * 4);
        float M = fmaxf(m0, m1);
        float fsc = exp2_fast(m0 - M);
        float fo = exp2_fast(m1 - M);
        float inv = 1.0f / (l0 * fsc + l1 * fo);

        u16* fb = (u16*)smem;              // [32][328] bf16, in-place merge
        if (pj == 1) {
            #pragma unroll
            for (int ct = 0; ct < 5; ++ct)
                #pragma unroll
                for (int e = 0; e < 16; ++e) {
                    int c = pc * 160 + ct * 32 + (e & 3) + 8 * (e >> 2) + 4 * hi;
                    fb[r * 328 + c] = f2b(o[ct][e] * fsc);
                }
        }
        __syncthreads();    // syncB
        if (pj == 0) {
            #pragma unroll
            for (int ct = 0; ct < 5; ++ct)
                #pragma unroll
                for (int g = 0; g < 4; ++g) {
                    int cb = pc * 160 + ct * 32 + 8 * g + 4 * hi;
                    u16* fr = &fb[r * 328 + cb];
                    float v0 = (o[ct][4 * g + 0] * fsc + b2f(fr[0])) * inv;
                    float v1 = (o[ct][4 * g + 1] * fsc + b2f(fr[1])) * inv;
                    float v2 = (o[ct][4 * g + 2] * fsc + b2f(fr[2])) * inv;
                    float v3 = (o[ct][4 * g + 3] * fsc + b2f(fr[3])) * inv;
                    *(unsigned*)(fr) = cvt_pk_bf16(v0, v1);
                    *(unsigned*)(fr + 2) = cvt_pk_bf16(v2, v3);
                }
        }
        __syncthreads();    // syncC
        #undef PV_BODY
    }

    // ---- common: store AO (32 q-rows x 320 ch) from smem [32][328] ----
    const u16* ob = (const u16*)smem;
    u16* AOb = AO + ((size_t)b * NN + i0) * CU;
    #pragma unroll
    for (int n = 0; n < 3; ++n) {
        int id = n * 384 + t;
        int row = id / 40, c8 = id % 40;
        bf16x8 val = *(const bf16x8*)(ob + row * 328 + c8 * 8);
        *(bf16x8*)(AOb + (size_t)row * CU + c8 * 8) = val;
    }
    if (t < 128) {
        int id = 1152 + t;
        int row = id / 40, c8 = id % 40;
        bf16x8 val = *(const bf16x8*)(ob + row * 328 + c8 * 8);
        *(bf16x8*)(AOb + (size_t)row * CU + c8 * 8) = val;
    }
}

extern "C" void kernel_launch(void* const* d_in, const int* in_sizes, int n_in,
                              void* d_out, int out_size, void* d_ws, size_t ws_size,
                              hipStream_t stream) {
    const float* unet  = (const float*)d_in[0];
    const float* janus = (const float*)d_in[1];
    const float* Wq = (const float*)d_in[2];
    const float* bq = (const float*)d_in[3];
    const float* Wk = (const float*)d_in[4];
    const float* bk = (const float*)d_in[5];
    const float* Wv = (const float*)d_in[6];
    const float* bv = (const float*)d_in[7];
    const float* Wo = (const float*)d_in[8];
    const float* bo = (const float*)d_in[9];
    float* out = (float*)d_out;

    char* ws = (char*)d_ws;
    u16* Xu  = (u16*)(ws + XU_OFF);
    u16* Xj  = (u16*)(ws + XJ_OFF);
    u16* Qb  = (u16*)(ws + QB_OFF);
    u16* Kb  = (u16*)(ws + KB_OFF);
    u16* Vb  = (u16*)(ws + VB_OFF);
    u16* wq  = (u16*)(ws + WQ_OFF);
    u16* wk  = (u16*)(ws + WK_OFF);
    u16* wv  = (u16*)(ws + WV_OFF);
    u16* wo  = (u16*)(ws + WO_OFF);
    u16* AO  = (u16*)(ws + AO_OFF);

    wcast_kernel<<<3024, 256, 0, stream>>>(Wq, Wk, Wv, Wo, wq, wk, wv, wo);

    transpose_cast_kernel<<<dim3(64, 5, NB), 256, 0, stream>>>(unet, Xu, CU, NN);
    transpose_cast_kernel<<<dim3(64, 16, NB), 256, 0, stream>>>(janus, Xj, CJ, NN);

    // Q pre-scaled by (1/16) * log2(e) so softmax runs in exp2 domain
    gemm_kernel<0, 320, 256><<<dim3(128, 4), 256, 0, stream>>>(
        Xu, wq, bq, Qb, nullptr, 0.0901684411f);
    gemm_kernel<3, 1024, 256><<<dim3(128, 4), 256, 0, stream>>>(
        Xj, wk, bk, Kb, nullptr, 1.0f);
    gemm_kernel<1, 1024, 320><<<dim3(128, 5), 256, 0, stream>>>(
        Xj, wv, bv, Vb, nullptr, 1.0f);

    attn_kernel<<<512, 384, 0, stream>>>(Qb, Kb, Vb, AO);

    gemm_kernel<2, 320, 320><<<dim3(128, 5), 256, 0, stream>>>(
        AO, wo, bo, out, unet, 1.0f);
}

// Round 11
// 260.926 us; speedup vs baseline: 1.2885x; 1.2885x over previous
//
#include <hip/hip_runtime.h>
#include <hip/hip_bf16.h>
#include <math.h>

// ---------------------------------------------------------------------------
// CrossModalAttention on MI355X (gfx950)
//   B=4, Cu=320, Cj=1024, H=W=64 (N=4096), ATTN_DIM=256, scale = 1/16
// Round 10: R8 wave-specialized attn (2 QK + 4 PV waves) with SINGLE-buffered
// K tile (32KB) -> total LDS 42,496 B so 2 blocks/CU reside (R8's 75KB only
// fit once). 2 barriers/tile: [QK(i) || PV(i-1)] -> barrier1 -> stage K[i+1]
// under softmax -> vmcnt(0) -> barrier2. In-place bf16 merge epilogue.
// ---------------------------------------------------------------------------

typedef unsigned short u16;
typedef __attribute__((ext_vector_type(8))) short bf16x8;
typedef __attribute__((ext_vector_type(4))) float f32x4;
typedef __attribute__((ext_vector_type(16))) float f32x16;
typedef __attribute__((ext_vector_type(4))) unsigned short u16x4;

#define NB 4
#define CU 320
#define CJ 1024
#define NN 4096
#define AD 256

// ws layout (bytes)
#define XU_OFF 0u
#define XJ_OFF 10485760u
#define QB_OFF 44040192u
#define KB_OFF 52428800u
#define VB_OFF 60817408u
#define WQ_OFF 71303168u
#define WK_OFF 71467008u
#define WV_OFF 71991296u
#define WO_OFF 72646656u
#define AO_OFF XU_OFF

__device__ __forceinline__ u16 f2b(float f) {
    union { float f; unsigned u; } v; v.f = f;
    unsigned u = v.u;
    unsigned r = (u + 0x7fffu + ((u >> 16) & 1u)) >> 16;
    return (u16)r;
}

__device__ __forceinline__ float b2f(u16 x) {
    union { unsigned u; float f; } v; v.u = ((unsigned)x) << 16;
    return v.f;
}

__device__ __forceinline__ unsigned cvt_pk_bf16(float lo, float hi) {
    unsigned r;
    asm("v_cvt_pk_bf16_f32 %0, %1, %2" : "=v"(r) : "v"(lo), "v"(hi));
    return r;
}

__device__ __forceinline__ float exp2_fast(float x) {
    float r;
    asm("v_exp_f32 %0, %1" : "=v"(r) : "v"(x));
    return r;
}

__device__ __forceinline__ void async_cp16(const u16* g, char* l) {
    __builtin_amdgcn_global_load_lds(
        (const __attribute__((address_space(1))) unsigned int*)g,
        (__attribute__((address_space(3))) unsigned int*)l, 16, 0, 0);
}

// ---------------- weight cast ----------------
__global__ void wcast_kernel(const float* __restrict__ Wq, const float* __restrict__ Wk,
                             const float* __restrict__ Wv, const float* __restrict__ Wo,
                             u16* __restrict__ wq, u16* __restrict__ wk,
                             u16* __restrict__ wv, u16* __restrict__ wo) {
    int id = blockIdx.x * 256 + threadIdx.x;
    if (id < 81920) { wq[id] = f2b(Wq[id]); return; }
    id -= 81920;
    if (id < 262144) { wk[id] = f2b(Wk[id]); return; }
    id -= 262144;
    if (id < 327680) { wv[id] = f2b(Wv[id]); return; }
    id -= 327680;
    if (id < 102400) { wo[id] = f2b(Wo[id]); }
}

// ---------------- transpose [C][N] f32 -> [N][C] bf16 ----------------
__global__ __launch_bounds__(256) void transpose_cast_kernel(
        const float* __restrict__ in, u16* __restrict__ out, int C, int Nn) {
    __shared__ float tile[64][65];
    int b = blockIdx.z;
    int n0 = blockIdx.x * 64, c0 = blockIdx.y * 64;
    const float* src = in + (size_t)b * C * Nn;
    u16* dst = out + (size_t)b * Nn * C;
    int t = threadIdx.x;
    int nl = t & 63, cl = t >> 6;
    #pragma unroll
    for (int k = 0; k < 16; ++k) {
        int c = cl + k * 4;
        tile[c][nl] = src[(size_t)(c0 + c) * Nn + n0 + nl];
    }
    __syncthreads();
    int cl2 = t & 63, nl2 = t >> 6;
    #pragma unroll
    for (int k = 0; k < 16; ++k) {
        int n = nl2 + k * 4;
        dst[(size_t)(n0 + n) * C + c0 + cl2] = f2b(tile[cl2][n]);
    }
}

// ---------------- unified GEMM: out = A(16384xKD) @ W(NOUTxKD)^T ----------------
template <int EPI, int KD, int NOUT>
__global__ __launch_bounds__(256, 2) void gemm_kernel(
        const u16* __restrict__ A, const u16* __restrict__ W,
        const float* __restrict__ bias, void* __restrict__ outp,
        const float* __restrict__ unet, float alpha) {
    __shared__ __align__(16) char smem[49152];
    const int t = threadIdx.x;
    const int lane = t & 63, wave = t >> 6;
    const int r = lane & 15, h = lane >> 4;
    const int wr = wave >> 1, wc = wave & 1;
    const int m0 = blockIdx.x * 128;
    const int bn0 = blockIdx.y * 64;

    int goffA[4], goffB[2];
    #pragma unroll
    for (int n = 0; n < 4; ++n) {
        int c = n * 256 + t;
        int row = c >> 3, s = c & 7;
        goffA[n] = (m0 + row) * KD + ((s ^ (row & 7)) << 3);
    }
    #pragma unroll
    for (int n = 0; n < 2; ++n) {
        int c = n * 256 + t;
        int row = c >> 3, s = c & 7;
        goffB[n] = (bn0 + row) * KD + ((s ^ (row & 7)) << 3);
    }
    const unsigned wb = (unsigned)(t & ~63) * 16u;

    #define GSTAGE(BUF, KT) do {                                                  \
        _Pragma("unroll")                                                         \
        for (int n_ = 0; n_ < 4; ++n_)                                            \
            async_cp16(A + goffA[n_] + (KT) * 64,                                 \
                       smem + (BUF) * 24576 + n_ * 4096 + wb);                    \
        _Pragma("unroll")                                                         \
        for (int n_ = 0; n_ < 2; ++n_)                                            \
            async_cp16(W + goffB[n_] + (KT) * 64,                                 \
                       smem + (BUF) * 24576 + 16384 + n_ * 4096 + wb);            \
    } while (0)

    f32x4 acc[4][2];
    #pragma unroll
    for (int fr = 0; fr < 4; ++fr)
        #pragma unroll
        for (int fc = 0; fc < 2; ++fc) acc[fr][fc] = (f32x4)0.0f;

    GSTAGE(0, 0);
    int buf = 0;
    const int KS = KD / 64;
    for (int kt = 0; kt < KS; ++kt) {
        if (kt < KS - 1) {
            GSTAGE(buf ^ 1, kt + 1);
            asm volatile("s_waitcnt vmcnt(6)" ::: "memory");
        } else {
            asm volatile("s_waitcnt vmcnt(0)" ::: "memory");
        }
        __builtin_amdgcn_s_barrier();
        asm volatile("" ::: "memory");
        const char* Ab = smem + buf * 24576;
        const char* Bb = smem + buf * 24576 + 16384;
        #pragma unroll
        for (int kk = 0; kk < 2; ++kk) {
            bf16x8 af[4], bf[2];
            #pragma unroll
            for (int fr = 0; fr < 4; ++fr) {
                int row = wr * 64 + fr * 16 + r;
                af[fr] = *(const bf16x8*)(Ab + row * 128 + (((kk * 4 + h) ^ (row & 7)) << 4));
            }
            #pragma unroll
            for (int fc = 0; fc < 2; ++fc) {
                int rowb = wc * 32 + fc * 16 + r;
                bf[fc] = *(const bf16x8*)(Bb + rowb * 128 + (((kk * 4 + h) ^ (rowb & 7)) << 4));
            }
            #pragma unroll
            for (int fr = 0; fr < 4; ++fr)
                #pragma unroll
                for (int fc = 0; fc < 2; ++fc)
                    acc[fr][fc] = __builtin_amdgcn_mfma_f32_16x16x32_bf16(
                        af[fr], bf[fc], acc[fr][fc], 0, 0, 0);
        }
        asm volatile("" ::: "memory");
        __builtin_amdgcn_s_barrier();
        asm volatile("" ::: "memory");
        buf ^= 1;
    }
    #undef GSTAGE

    const int mw = m0 + wr * 64;
    const int ob0 = bn0 + wc * 32;

    if (EPI == 0) {
        u16* out = (u16*)outp;
        #pragma unroll
        for (int fc = 0; fc < 2; ++fc) {
            int o = ob0 + fc * 16 + r;
            float bs = bias[o];
            #pragma unroll
            for (int fr = 0; fr < 4; ++fr)
                #pragma unroll
                for (int rr = 0; rr < 4; ++rr) {
                    int mrow = mw + fr * 16 + h * 4 + rr;
                    out[(size_t)mrow * NOUT + o] = f2b((acc[fr][fc][rr] + bs) * alpha);
                }
        }
    } else if (EPI == 1) {
        // transpose via LDS then store in MFMA B-fragment order V'[b][ct][j16][lane][8]
        u16* tile = (u16*)(smem + wave * 4608);
        #pragma unroll
        for (int fc = 0; fc < 2; ++fc) {
            int o = ob0 + fc * 16 + r;
            float bs = bias[o];
            #pragma unroll
            for (int fr = 0; fr < 4; ++fr) {
                u16x4 v4;
                #pragma unroll
                for (int rr = 0; rr < 4; ++rr) v4[rr] = f2b(acc[fr][fc][rr] + bs);
                *(u16x4*)(tile + (fc * 16 + r) * 72 + fr * 16 + h * 4) = v4;
            }
        }
        __builtin_amdgcn_s_waitcnt(0);
        u16* Vout = (u16*)outp;
        int bb = mw >> 12, nb = mw & 4095;
        #pragma unroll
        for (int g = 0; g < 4; ++g) {
            int chunk = g * 64 + lane;
            int row = chunk >> 3, ns = chunk & 7;
            int ch = ob0 + row;
            int j = nb + ns * 8;
            bf16x8 val = *(const bf16x8*)(tile + row * 72 + ns * 8);
            size_t off = (size_t)bb * CU * NN + (size_t)(ch >> 5) * (NN * 32)
                       + (size_t)(j >> 4) * 512
                       + (size_t)((ch & 31) + ((j >> 3) & 1) * 32) * 8 + (j & 7);
            *(bf16x8*)(Vout + off) = val;
        }
    } else {
        float* tile = (float*)(smem + wave * 8704);   // [32][68] f32
        #pragma unroll
        for (int fc = 0; fc < 2; ++fc)
            #pragma unroll
            for (int fr = 0; fr < 4; ++fr)
                *(f32x4*)(tile + (fc * 16 + r) * 68 + fr * 16 + h * 4) = acc[fr][fc];
        __builtin_amdgcn_s_waitcnt(0);
        float* out = (float*)outp;
        int bb = mw >> 12, nb = mw & 4095;
        #pragma unroll
        for (int g = 0; g < 8; ++g) {
            int chunk = g * 64 + lane;
            int row = chunk >> 4, ns = chunk & 15;
            int o = ob0 + row;
            size_t base = (size_t)bb * CU * NN + (size_t)o * NN + nb + ns * 4;
            f32x4 v = *(const f32x4*)(tile + row * 68 + ns * 4);
            f32x4 u = *(const f32x4*)(unet + base);
            float bs = bias[o];
            f32x4 res;
            #pragma unroll
            for (int rr = 0; rr < 4; ++rr) res[rr] = v[rr] + bs + u[rr];
            *(f32x4*)(out + base) = res;
        }
    }
}

// ---------------- flash attention (round-10) ----------------
// Q: [B][N][256] bf16 (pre-scaled log2e/16), K: [B][N][256],
// V': [B][ct 10][j16 256][lane 64][8] bf16 (fragment order).
// 512 blocks x 384 thr (6 waves): waves 0-1 = QK(jw), waves 2-5 = PV(pj,pc).
// LDS 42,496 B: kbuf 32KB @0 (single buffer); pbuf 2 parity x 4608 @32768
// (P frags @+0, al @+4096, flag @+4352); mlb @41984. 2 blocks/CU.
// Schedule/tile: [QK(i) || PV(i-1)] -> lgkm -> bar1 -> STAGE K[i+1] ->
// softmax+P-publish -> lgkm -> vmcnt(0) -> bar2.
__global__ __launch_bounds__(384, 3) void attn_kernel(
        const u16* __restrict__ Q, const u16* __restrict__ K,
        const u16* __restrict__ V, u16* __restrict__ AO) {
    __shared__ __align__(16) char smem[42496];

    const int t = threadIdx.x;
    const int lane = t & 63;
    const int wave = t >> 6;          // 0..5
    const int r = lane & 31, hi = lane >> 5;

    int linear = blockIdx.x;
    int swz = (linear & 7) * 64 + (linear >> 3);
    int b = swz >> 7;
    int i0 = (swz & 127) * 32;

    const u16* Qb = Q + ((size_t)b * NN + i0) * AD;
    const u16* Kb = K + (size_t)b * NN * AD;
    const u16* Vb = V + (size_t)b * CU * NN;

    // K staging: 64j x 256ch tile = 2048 chunks of 16B over 384 threads
    int goff[6];
    unsigned ldsoff[6];
    #pragma unroll
    for (int n = 0; n < 6; ++n) {
        int id = n * 384 + t;
        int row = (id >> 5) & 63;
        int c16 = id & 31;
        goff[n] = row * 256 + ((c16 ^ (row & 31)) << 3);
        ldsoff[n] = (unsigned)(n * 384 + (t & ~63)) * 16u;
    }

    #define STAGE(KP) do {                                                        \
        _Pragma("unroll")                                                         \
        for (int n_ = 0; n_ < 5; ++n_)                                            \
            async_cp16((KP) + goff[n_], smem + ldsoff[n_]);                       \
        if (t < 128)                                                              \
            async_cp16((KP) + goff[5], smem + ldsoff[5]);                         \
    } while (0)

    STAGE(Kb);
    asm volatile("s_waitcnt vmcnt(0)" ::: "memory");
    __builtin_amdgcn_s_barrier();     // K[0] ready for all
    asm volatile("" ::: "memory");

    if (wave < 2) {
        // ================= QK role =================
        const int jw = wave;
        bf16x8 q[16];
        #pragma unroll
        for (int kk = 0; kk < 16; ++kk)
            q[kk] = *(const bf16x8*)(Qb + (size_t)r * AD + kk * 16 + hi * 8);
        float m = -INFINITY, lsum = 0.0f;

        for (int i = 0; i < 64; ++i) {
            // ---- QK(i) from kbuf ----
            const char* Kt = smem + jw * 16384;
            f32x16 sa = (f32x16)0.0f, sb = (f32x16)0.0f;
            __builtin_amdgcn_s_setprio(1);
            #pragma unroll
            for (int kk = 0; kk < 8; ++kk) {
                bf16x8 k0 = *(const bf16x8*)(Kt + r * 512 + (((2 * kk + hi) ^ r) << 4));
                bf16x8 k1 = *(const bf16x8*)(Kt + r * 512 + (((2 * (kk + 8) + hi) ^ r) << 4));
                sa = __builtin_amdgcn_mfma_f32_32x32x16_bf16(k0, q[kk], sa, 0, 0, 0);
                sb = __builtin_amdgcn_mfma_f32_32x32x16_bf16(k1, q[kk + 8], sb, 0, 0, 0);
            }
            __builtin_amdgcn_s_setprio(0);
            f32x16 s = sa + sb;

            asm volatile("s_waitcnt lgkmcnt(0)" ::: "memory");   // kbuf reads done
            __builtin_amdgcn_s_barrier();                        // bar1
            asm volatile("" ::: "memory");
            if (i < 63) STAGE(Kb + (i + 1) * 16384);             // restage under softmax

            // ---- softmax(i), exp2 domain, defer-max THR=8 ----
            float x0 = fmaxf(s[0], s[1]),   x1 = fmaxf(s[2], s[3]);
            float x2 = fmaxf(s[4], s[5]),   x3 = fmaxf(s[6], s[7]);
            float x4 = fmaxf(s[8], s[9]),   x5 = fmaxf(s[10], s[11]);
            float x6 = fmaxf(s[12], s[13]), x7 = fmaxf(s[14], s[15]);
            float pmax = fmaxf(fmaxf(fmaxf(x0, x1), fmaxf(x2, x3)),
                               fmaxf(fmaxf(x4, x5), fmaxf(x6, x7)));
            pmax = fmaxf(pmax, __shfl_xor(pmax, 32));
            char* pb = smem + 32768 + (i & 1) * 4608;
            int fl = __any(pmax > m + 8.0f) ? 1 : 0;
            if (fl) {
                float mn = fmaxf(m, pmax);
                float al = exp2_fast(m - mn);
                m = mn;
                lsum *= al;
                if (lane < 32) *(float*)(pb + 4096 + jw * 128 + r * 4) = al;
            }
            if (lane == 0) *(int*)(pb + 4352 + jw * 4) = fl;
            float p[16];
            #pragma unroll
            for (int e = 0; e < 16; ++e) p[e] = exp2_fast(s[e] - m);
            float y0 = (p[0] + p[1]) + (p[2] + p[3]);
            float y1 = (p[4] + p[5]) + (p[6] + p[7]);
            float y2 = (p[8] + p[9]) + (p[10] + p[11]);
            float y3 = (p[12] + p[13]) + (p[14] + p[15]);
            float ps = (y0 + y1) + (y2 + y3);
            ps += __shfl_xor(ps, 32);
            lsum += ps;

            // P -> B-operand fragments, publish
            #pragma unroll
            for (int ks = 0; ks < 2; ++ks) {
                unsigned a0 = cvt_pk_bf16(p[8 * ks + 0], p[8 * ks + 1]);
                unsigned a1 = cvt_pk_bf16(p[8 * ks + 2], p[8 * ks + 3]);
                unsigned b0 = cvt_pk_bf16(p[8 * ks + 4], p[8 * ks + 5]);
                unsigned b1 = cvt_pk_bf16(p[8 * ks + 6], p[8 * ks + 7]);
                asm("v_permlane32_swap_b32 %0, %1" : "+v"(a0), "+v"(b0));
                asm("v_permlane32_swap_b32 %0, %1" : "+v"(a1), "+v"(b1));
                union { unsigned w[4]; bf16x8 v; } u;
                u.w[0] = a0; u.w[1] = a1; u.w[2] = b0; u.w[3] = b1;
                *(bf16x8*)(pb + jw * 2048 + ks * 1024 + lane * 16) = u.v;
            }
            asm volatile("s_waitcnt lgkmcnt(0)" ::: "memory");   // P published
            if (i < 63) asm volatile("s_waitcnt vmcnt(0)" ::: "memory"); // K[i+1] in
            __builtin_amdgcn_s_barrier();                        // bar2
            asm volatile("" ::: "memory");
        }
        // publish m/l
        if (lane < 32) {
            *(float*)(smem + 41984 + jw * 128 + r * 4) = m;
            *(float*)(smem + 41984 + 256 + jw * 128 + r * 4) = lsum;
        }
        __syncthreads();    // syncA
        __syncthreads();    // syncB
        __syncthreads();    // syncC
    } else {
        // ================= PV role =================
        const int pvid = wave - 2;
        const int pj = pvid & 1;        // which jw's P
        const int pc = pvid >> 1;       // 160-ch half
        f32x16 o[5];
        #pragma unroll
        for (int ct = 0; ct < 5; ++ct) o[ct] = (f32x16)0.0f;
        const u16* vb = Vb + (size_t)(pc * 5) * 131072 + lane * 8;

        #define PV_BODY(TI) do {                                                  \
            const char* pb = smem + 32768 + ((TI) & 1) * 4608;                    \
            int fl = *(volatile const int*)(pb + 4352 + pj * 4);                  \
            bf16x8 vfA[5], vfB[5];                                                \
            _Pragma("unroll")                                                     \
            for (int c = 0; c < 5; ++c)                                           \
                vfA[c] = *(const bf16x8*)(vb + (size_t)c * 131072 +               \
                                          ((TI) * 4 + pj * 2 + 0) * 512);         \
            _Pragma("unroll")                                                     \
            for (int c = 0; c < 5; ++c)                                           \
                vfB[c] = *(const bf16x8*)(vb + (size_t)c * 131072 +               \
                                          ((TI) * 4 + pj * 2 + 1) * 512);         \
            bf16x8 pf0 = *(const bf16x8*)(pb + pj * 2048 + lane * 16);            \
            bf16x8 pf1 = *(const bf16x8*)(pb + pj * 2048 + 1024 + lane * 16);     \
            if (fl) {                                                             \
                float alv = *(volatile const float*)(pb + 4096 + pj * 128 +       \
                                                     (lane & 31) * 4);            \
                _Pragma("unroll")                                                 \
                for (int ct = 0; ct < 5; ++ct) o[ct] *= alv;                      \
            }                                                                     \
            __builtin_amdgcn_s_setprio(1);                                        \
            _Pragma("unroll")                                                     \
            for (int ct = 0; ct < 5; ++ct)                                        \
                o[ct] = __builtin_amdgcn_mfma_f32_32x32x16_bf16(vfA[ct], pf0,     \
                                                                o[ct], 0, 0, 0); \
            _Pragma("unroll")                                                     \
            for (int ct = 0; ct < 5; ++ct)                                        \
                o[ct] = __builtin_amdgcn_mfma_f32_32x32x16_bf16(vfB[ct], pf1,     \
                                                                o[ct], 0, 0, 0); \
            __builtin_amdgcn_s_setprio(0);                                        \
        } while (0)

        for (int i = 0; i < 64; ++i) {
            if (i >= 1) PV_BODY(i - 1);       // concurrent with QK(i)
            __builtin_amdgcn_s_barrier();     // bar1
            asm volatile("" ::: "memory");
            if (i < 63) STAGE(Kb + (i + 1) * 16384);
            if (i < 63) asm volatile("s_waitcnt vmcnt(0)" ::: "memory");
            __builtin_amdgcn_s_barrier();     // bar2
            asm volatile("" ::: "memory");
        }
        PV_BODY(63);

        __syncthreads();    // syncA: m/l published, kbuf dead
        float m0 = *(const float*)(smem + 41984 + pj * 128 + r * 4);
        float l0 = *(const float*)(smem + 41984 + 256 + pj * 128 + r * 4);
        float m1 = *(const float*)(smem + 41984 + (pj ^ 1) * 128 + r * 4);
        float l1 = *(const float*)(smem + 41984 + 256 + (pj ^ 1) * 128 + r * 4);
        float M = fmaxf(m0, m1);
        float fsc = exp2_fast(m0 - M);
        float fo = exp2_fast(m1 - M);
        float inv = 1.0f / (l0 * fsc + l1 * fo);

        u16* fb = (u16*)smem;              // [32][328] bf16, in-place merge
        if (pj == 1) {
            #pragma unroll
            for (int ct = 0; ct < 5; ++ct)
                #pragma unroll
                for (int e = 0; e < 16; ++e) {
                    int c = pc * 160 + ct * 32 + (e & 3) + 8 * (e >> 2) + 4 * hi;
                    fb[r * 328 + c] = f2b(o[ct][e] * fsc);
                }
        }
        __syncthreads();    // syncB
        if (pj == 0) {
            #pragma unroll
            for (int ct = 0; ct < 5; ++ct)
                #pragma unroll
                for (int g = 0; g < 4; ++g) {
                    int cb = pc * 160 + ct * 32 + 8 * g + 4 * hi;
                    u16* fr = &fb[r * 328 + cb];
                    float v0 = (o[ct][4 * g + 0] * fsc + b2f(fr[0])) * inv;
                    float v1 = (o[ct][4 * g + 1] * fsc + b2f(fr[1])) * inv;
                    float v2 = (o[ct][4 * g + 2] * fsc + b2f(fr[2])) * inv;
                    float v3 = (o[ct][4 * g + 3] * fsc + b2f(fr[3])) * inv;
                    *(unsigned*)(fr) = cvt_pk_bf16(v0, v1);
                    *(unsigned*)(fr + 2) = cvt_pk_bf16(v2, v3);
                }
        }
        __syncthreads();    // syncC
        #undef PV_BODY
    }

    // ---- common: store AO (32 q-rows x 320 ch) from smem [32][328] ----
    const u16* ob = (const u16*)smem;
    u16* AOb = AO + ((size_t)b * NN + i0) * CU;
    #pragma unroll
    for (int n = 0; n < 3; ++n) {
        int id = n * 384 + t;
        int row = id / 40, c8 = id % 40;
        bf16x8 val = *(const bf16x8*)(ob + row * 328 + c8 * 8);
        *(bf16x8*)(AOb + (size_t)row * CU + c8 * 8) = val;
    }
    if (t < 128) {
        int id = 1152 + t;
        int row = id / 40, c8 = id % 40;
        bf16x8 val = *(const bf16x8*)(ob + row * 328 + c8 * 8);
        *(bf16x8*)(AOb + (size_t)row * CU + c8 * 8) = val;
    }
    #undef STAGE
}

extern "C" void kernel_launch(void* const* d_in, const int* in_sizes, int n_in,
                              void* d_out, int out_size, void* d_ws, size_t ws_size,
                              hipStream_t stream) {
    const float* unet  = (const float*)d_in[0];
    const float* janus = (const float*)d_in[1];
    const float* Wq = (const float*)d_in[2];
    const float* bq = (const float*)d_in[3];
    const float* Wk = (const float*)d_in[4];
    const float* bk = (const float*)d_in[5];
    const float* Wv = (const float*)d_in[6];
    const float* bv = (const float*)d_in[7];
    const float* Wo = (const float*)d_in[8];
    const float* bo = (const float*)d_in[9];
    float* out = (float*)d_out;

    char* ws = (char*)d_ws;
    u16* Xu  = (u16*)(ws + XU_OFF);
    u16* Xj  = (u16*)(ws + XJ_OFF);
    u16* Qb  = (u16*)(ws + QB_OFF);
    u16* Kb  = (u16*)(ws + KB_OFF);
    u16* Vb  = (u16*)(ws + VB_OFF);
    u16* wq  = (u16*)(ws + WQ_OFF);
    u16* wk  = (u16*)(ws + WK_OFF);
    u16* wv  = (u16*)(ws + WV_OFF);
    u16* wo  = (u16*)(ws + WO_OFF);
    u16* AO  = (u16*)(ws + AO_OFF);

    wcast_kernel<<<3024, 256, 0, stream>>>(Wq, Wk, Wv, Wo, wq, wk, wv, wo);

    transpose_cast_kernel<<<dim3(64, 5, NB), 256, 0, stream>>>(unet, Xu, CU, NN);
    transpose_cast_kernel<<<dim3(64, 16, NB), 256, 0, stream>>>(janus, Xj, CJ, NN);

    // Q pre-scaled by (1/16) * log2(e) so softmax runs in exp2 domain
    gemm_kernel<0, 320, 256><<<dim3(128, 4), 256, 0, stream>>>(
        Xu, wq, bq, Qb, nullptr, 0.0901684411f);
    gemm_kernel<0, 1024, 256><<<dim3(128, 4), 256, 0, stream>>>(
        Xj, wk, bk, Kb, nullptr, 1.0f);
    gemm_kernel<1, 1024, 320><<<dim3(128, 5), 256, 0, stream>>>(
        Xj, wv, bv, Vb, nullptr, 1.0f);

    attn_kernel<<<512, 384, 0, stream>>>(Qb, Kb, Vb, AO);

    gemm_kernel<2, 320, 320><<<dim3(128, 5), 256, 0, stream>>>(
        AO, wo, bo, out, unet, 1.0f);
}